// Round 7
// baseline (277.321 us; speedup 1.0000x reference)
//
#include <hip/hip_runtime.h>

// Problem constants
#define NN    65536       // H*W (H=W=256)
#define NBLK  512         // softmax partials per batch (one per wave)
#define TPW   4           // tiles (of 32 px) per wave

typedef short bf16x8 __attribute__((ext_vector_type(8)));
typedef float f32x4v __attribute__((ext_vector_type(4)));
typedef unsigned short ushort_t;
typedef unsigned int uint_t;

// ---- main_kernel LDS layout (bytes) ----
// xhi [128 rows][144 B] (wave w owns rows w*32..w*32+31; chunk XOR-swizzled)
// xlo same; each wave's 4608-B xlo slice is re-aliased (in program order,
// wave-private, DS pipe in-order) as: lga (32x28 f32 = 3584 B) then
// p_lds (16 x 40 bf16 = 1280 B). No cross-wave LDS traffic at all.
#define XLO_OFF 18432
#define SLICE   4608
#define LGSTR   28
#define PSTR    40
#define SMEM_BYTES 36864          // 4 blocks/CU = 16 waves/CU

// ---- workspace byte offsets ----
#define WTHI_B  0                 // bf16 [8][32][64] = 32768 B
#define WTLO_B  32768
#define CJ_B    65536             // f32 [8][24]
#define PM_B    66304             // f32 [8*NBLK*8] = 131072 B
#define PL_B    197376
#define PSP_B   328448            // f32 [..][2] = 262144 B
#define PSX_B   590592            // f32 [..][64] = 8 MB
#define Q_B     8979200           // f32 [8][8][8][68]
#define QSTR    68

// ---------- helpers ----------
__device__ __forceinline__ uint_t bf16_rne_bits(float f) {
  uint_t u = __float_as_uint(f);
  return (u + 0x7FFFu + ((u >> 16) & 1u)) >> 16;
}
// packed f32->bf16 RNE (identical rounding to bf16_rne_bits), 1 inst per pair
__device__ __forceinline__ uint_t cvt_pk_bf16(float a, float b) {
  uint_t r;
  asm("v_cvt_pk_bf16_f32 %0, %1, %2" : "=v"(r) : "v"(a), "v"(b));
  return r;
}
template <int CTRL, int RMASK = 0xf>
__device__ __forceinline__ float dpp_add(float x) {
  int t = __builtin_amdgcn_update_dpp(0, __float_as_int(x), CTRL, RMASK, 0xf, false);
  return x + __int_as_float(t);
}
template <int CTRL, int RMASK = 0xf>
__device__ __forceinline__ float dpp_maxs(float x) {
  int t = __builtin_amdgcn_update_dpp((int)0xFF800000u, __float_as_int(x), CTRL, RMASK, 0xf, false);
  return fmaxf(x, __int_as_float(t));
}
// 32-lane-half reductions (independent halves; result valid at lanes 31 and 63).
__device__ __forceinline__ float half_sum(float x) {
  x = dpp_add<0x111>(x); x = dpp_add<0x112>(x); x = dpp_add<0x114>(x);
  x = dpp_add<0x118>(x); x = dpp_add<0x142, 0xA>(x);
  return x;
}
__device__ __forceinline__ float half_max(float x) {
  x = dpp_maxs<0x111>(x); x = dpp_maxs<0x112>(x); x = dpp_maxs<0x114>(x);
  x = dpp_maxs<0x118>(x); x = dpp_maxs<0x142, 0xA>(x);
  return x;
}
// broadcast the half-reduction result (at lanes 31/63) to all lanes
__device__ __forceinline__ float bcast_half(float x, bool hi_half) {
  const int v0 = __builtin_amdgcn_readlane(__float_as_int(x), 31);
  const int v1 = __builtin_amdgcn_readlane(__float_as_int(x), 63);
  return __int_as_float(hi_half ? v1 : v0);
}

// ---------------- K0: effective weights, split-bf16, B-fragment layout ----------------
__global__ __launch_bounds__(64) void prep_kernel(
    const float* __restrict__ z,  const float* __restrict__ Wq, const float* __restrict__ bq,
    const float* __restrict__ Wk, const float* __restrict__ bk,
    const float* __restrict__ Wp, const float* __restrict__ bp,
    ushort_t* __restrict__ WThi, ushort_t* __restrict__ WTlo, float* __restrict__ Cj)
{
  const int h = blockIdx.x, b = blockIdx.y, t = threadIdx.x;
  __shared__ float q[32];
  if (t < 32) {
    const int e = h*32 + t;
    float a = bq[e];
    const float* zr = z + b*64;
    const float* wr = Wq + e*64;
    #pragma unroll 8
    for (int c = 0; c < 64; ++c) a += zr[c]*wr[c];
    q[t] = a;
  }
  __syncthreads();
  const int c = t;
  float w[3] = {0.f, 0.f, 0.f};
  #pragma unroll 4
  for (int hd = 0; hd < 32; ++hd) {
    const float qk = q[hd] * Wk[(h*32+hd)*64 + c];
    w[0] += qk * bp[hd];
    w[1] += qk * Wp[hd*2+0];
    w[2] += qk * Wp[hd*2+1];
  }
  #pragma unroll
  for (int j = 0; j < 3; ++j) {
    const int coeff = h*3 + j;
    const uint_t hb = bf16_rne_bits(w[j]);
    const float  fh = __uint_as_float(hb << 16);
    const uint_t lb = bf16_rne_bits(w[j] - fh);
    WThi[(b*32 + coeff)*64 + c] = (ushort_t)hb;
    WTlo[(b*32 + coeff)*64 + c] = (ushort_t)lb;
  }
  if (h == 0) {
    #pragma unroll
    for (int r = 0; r < 8; ++r) {
      WThi[(b*32 + 24 + r)*64 + c] = 0;
      WTlo[(b*32 + 24 + r)*64 + c] = 0;
    }
  }
  if (t < 3) {
    float s = 0.f;
    for (int hd = 0; hd < 32; ++hd) {
      const float m = (t == 0) ? bp[hd] : Wp[hd*2 + (t-1)];
      s += q[hd] * m * bk[h*32+hd];
    }
    Cj[b*24 + h*3 + t] = s;
  }
}

// ---------------- K1: wave-autonomous, zero barriers, register-pipelined ----------------
// 256 threads / 4 waves. Each WAVE independently processes 4 tiles of 32 px with
// an exact online softmax, producing one partial set per wave (NBLK=512/batch).
__global__ __launch_bounds__(256, 4) void main_kernel(
    const float* __restrict__ x, const float* __restrict__ pos,
    const ushort_t* __restrict__ WThi, const ushort_t* __restrict__ WTlo,
    const float* __restrict__ Cj,
    float* __restrict__ Pm, float* __restrict__ Pl,
    float* __restrict__ Psp, float* __restrict__ Psx)
{
  extern __shared__ char smc[];
  const int t   = threadIdx.x;
  const int b   = blockIdx.y;
  const int w   = t >> 6, lid = t & 63;
  const int c0  = lid & 15, q4 = lid >> 4;
  const int hg  = lid >> 5, pxl = lid & 31;
  const bool hihalf = (lid >= 32);
  const int wave_id = blockIdx.x*4 + w;      // 0..511 per batch
  const int tile0   = wave_id * TPW;

  char* xhiB  = smc;
  char* xloB  = smc + XLO_OFF;
  char* slice = xloB + w*SLICE;              // wave-private lga/p_lds region

  // ---- B-fragments (once per wave; L2-hot) ----
  bf16x8 bh[2][2], bl[2][2];
  {
    const ushort_t* wtb_h = WThi + b*2048;
    const ushort_t* wtb_l = WTlo + b*2048;
    #pragma unroll
    for (int nt = 0; nt < 2; ++nt)
      #pragma unroll
      for (int ks = 0; ks < 2; ++ks) {
        const int off = (nt*16 + c0)*64 + ks*32 + q4*8;
        bh[nt][ks] = *(const bf16x8*)(wtb_h + off);
        bl[nt][ks] = *(const bf16x8*)(wtb_l + off);
      }
  }

  // ---- wave-constant params ----
  float cj[12];
  {
    const float* cjp = Cj + b*24 + hg*12;
    #pragma unroll
    for (int k = 0; k < 12; ++k) cj[k] = cjp[k];
  }
  const float gxf = (float)(wave_id >> 1);   // gx constant over the wave's 4 tiles
  float rxh[4], py[4];
  #pragma unroll
  for (int hl = 0; hl < 4; ++hl) {
    const int h = hg*4 + hl;
    rxh[hl] = gxf - pos[(b*8+h)*2 + 0];
    py[hl]  = pos[(b*8+h)*2 + 1];
  }

  // ---- staging constants + prologue loads (tile 0) ----
  const int qd  = lid & 7;                   // pixel quad: local px = 4*qd + i
  const int g   = lid >> 3;                  // channel octet
  const int swz = (4*w + (qd >> 1)) & 7;
  const int chnk = (g ^ swz) * 16;
  const float* xg = x + (size_t)b*64*NN + (size_t)g*8*NN + (size_t)tile0*32 + 4*qd;
  f32x4v v[8];
  #pragma unroll
  for (int j = 0; j < 8; ++j) v[j] = *(const f32x4v*)(xg + (size_t)j*NN);

  // ---- online-softmax state (per head-group; L/SJ valid at lanes 31/63) ----
  float Mh[4], Lh[4], SJh[4];
  #pragma unroll
  for (int hl = 0; hl < 4; ++hl) { Mh[hl] = -1e30f; Lh[hl] = 0.f; SJh[hl] = 0.f; }
  float sx[16];                               // SX accumulator, valid at q4<2
  #pragma unroll
  for (int i = 0; i < 16; ++i) sx[i] = 0.f;

  for (int it = 0; it < TPW; ++it) {
    // ---- cvt + LDS write of tile it (consumes v) ----
    #pragma unroll
    for (int i = 0; i < 4; ++i) {
      uint_t H[4], L[4];
      #pragma unroll
      for (int jp = 0; jp < 4; ++jp) {
        const float f0 = v[2*jp][i], f1 = v[2*jp+1][i];
        const uint_t hpk = cvt_pk_bf16(f0, f1);
        const float h0 = __uint_as_float(hpk << 16);
        const float h1 = __uint_as_float(hpk & 0xFFFF0000u);
        const uint_t l0 = __float_as_uint(f0 - h0);
        const uint_t l1 = __float_as_uint(f1 - h1);
        H[jp] = hpk;
        L[jp] = __builtin_amdgcn_perm(l1, l0, 0x07060302u);  // {hi16(l1),hi16(l0)}
      }
      const int row = w*32 + 4*qd + i;
      *(uint4*)(xhiB + row*144 + chnk) = make_uint4(H[0], H[1], H[2], H[3]);
      *(uint4*)(xloB + row*144 + chnk) = make_uint4(L[0], L[1], L[2], L[3]);
    }

    // ---- issue tile it+1 loads (hidden under this tile's compute) ----
    if (it + 1 < TPW) {
      xg += 32;
      #pragma unroll
      for (int j = 0; j < 8; ++j) v[j] = *(const f32x4v*)(xg + (size_t)j*NN);
    }

    // ---- phase A (wave-private rows) ----
    f32x4v acc[2][2];
    #pragma unroll
    for (int mt = 0; mt < 2; ++mt) { acc[mt][0] = (f32x4v)0.f; acc[mt][1] = (f32x4v)0.f; }
    #pragma unroll
    for (int mt = 0; mt < 2; ++mt) {
      const int row  = w*32 + mt*16 + c0;
      const int srow = (4*w + 2*mt + (c0 >> 3)) & 7;
      const int ch0  = (q4 ^ srow) * 16;
      const char* rh = xhiB + row*144;
      const char* rl = xloB + row*144;
      bf16x8 ah0 = *(const bf16x8*)(rh + ch0);
      bf16x8 ah1 = *(const bf16x8*)(rh + (ch0 ^ 64));
      bf16x8 al0 = *(const bf16x8*)(rl + ch0);
      bf16x8 al1 = *(const bf16x8*)(rl + (ch0 ^ 64));
      #pragma unroll
      for (int nt = 0; nt < 2; ++nt) {
        f32x4v a = acc[mt][nt];
        a = __builtin_amdgcn_mfma_f32_16x16x32_bf16(ah0, bh[nt][0], a, 0, 0, 0);
        a = __builtin_amdgcn_mfma_f32_16x16x32_bf16(ah1, bh[nt][1], a, 0, 0, 0);
        a = __builtin_amdgcn_mfma_f32_16x16x32_bf16(ah0, bl[nt][0], a, 0, 0, 0);
        a = __builtin_amdgcn_mfma_f32_16x16x32_bf16(ah1, bl[nt][1], a, 0, 0, 0);
        a = __builtin_amdgcn_mfma_f32_16x16x32_bf16(al0, bh[nt][0], a, 0, 0, 0);
        a = __builtin_amdgcn_mfma_f32_16x16x32_bf16(al1, bh[nt][1], a, 0, 0, 0);
        acc[mt][nt] = a;
      }
    }

    // ---- lga transpose (wave-private; aliases own xlo rows, now dead) ----
    {
      float* lga_w = (float*)slice;
      #pragma unroll
      for (int mt = 0; mt < 2; ++mt)
        #pragma unroll
        for (int r = 0; r < 4; ++r) {
          const int prow = mt*16 + q4*4 + r;   // local 0..31
          lga_w[prow*LGSTR + c0] = acc[mt][0][r];
          if (c0 < 8) lga_w[prow*LGSTR + 16 + c0] = acc[mt][1][r];
        }
    }

    // ---- logits ----
    float a12[12];
    {
      const float4* ap = (const float4*)((float*)slice + pxl*LGSTR + hg*12);
      #pragma unroll
      for (int r = 0; r < 3; ++r) *(float4*)(a12 + 4*r) = ap[r];
    }
    const float tf = (float)((((tile0 + it) & 7) << 5) + pxl);   // gy = n & 255
    float lg[4];
    #pragma unroll
    for (int hl = 0; hl < 4; ++hl) {
      const float a0 = a12[hl*3+0] + cj[hl*3+0];
      const float a1 = a12[hl*3+1] + cj[hl*3+1];
      const float a2 = a12[hl*3+2] + cj[hl*3+2];
      lg[hl] = (a0 + rxh[hl]*a1 + (tf - py[hl])*a2) * 0.17677669529663687f;
    }

    // ---- per-group tile max (all-lane), online update ----
    float rs[4], p[4];
    #pragma unroll
    for (int hl = 0; hl < 4; ++hl) {
      const float mt_ = bcast_half(half_max(lg[hl]), hihalf);
      const float Mn  = fmaxf(Mh[hl], mt_);
      rs[hl] = __expf(Mh[hl] - Mn);
      p[hl]  = __expf(lg[hl] - Mn);
      Mh[hl] = Mn;
    }
    #pragma unroll
    for (int hl = 0; hl < 4; ++hl) {
      const float sp  = half_sum(p[hl]);
      const float spj = half_sum(p[hl] * tf);
      Lh[hl]  = Lh[hl]*rs[hl]  + sp;    // valid at lanes 31/63
      SJh[hl] = SJh[hl]*rs[hl] + spj;
    }

    // ---- P -> bf16 hi/lo into wave-private p_lds (aliases lga, now dead) ----
    {
      ushort_t* pls = (ushort_t*)slice;
      #pragma unroll
      for (int hl = 0; hl < 4; ++hl) {
        const int h = hg*4 + hl;
        const uint_t hb = bf16_rne_bits(p[hl]);
        const float  hf = __uint_as_float(hb << 16);
        const uint_t lb = __float_as_uint(p[hl] - hf) >> 16;
        pls[h*PSTR + pxl]     = (ushort_t)hb;
        pls[(h+8)*PSTR + pxl] = (ushort_t)lb;
      }
    }

    // ---- rescale factors for this lane's SX heads (q4 odd needs other half's rs) ----
    float rsu[4];
    #pragma unroll
    for (int r = 0; r < 4; ++r) {
      const float ro = __shfl_xor(rs[r], 32, 64);
      rsu[r] = (q4 & 1) ? ro : rs[r];
    }

    // ---- phase B (MFMA): D[16][64] = P(16x32) . X(32px x 64ch); accumulate in regs ----
    {
      const ushort_t* pls = (const ushort_t*)slice;
      const bf16x8 afr = *(const bf16x8*)(pls + c0*PSTR + q4*8);
      const int srow_b = (4*w + q4) & 7;
      #pragma unroll
      for (int nt = 0; nt < 4; ++nt) {
        const int gch  = nt*2 + (c0 >> 3);
        const char* base = xhiB + (w*32 + q4*8)*144 + ((gch ^ srow_b)*16) + (c0 & 7)*2;
        bf16x8 bfr;
        #pragma unroll
        for (int j = 0; j < 8; ++j) bfr[j] = *(const short*)(base + j*144);
        f32x4v accB = __builtin_amdgcn_mfma_f32_16x16x32_bf16(afr, bfr, (f32x4v)0.f, 0, 0, 0);
        #pragma unroll
        for (int r = 0; r < 4; ++r) {
          const float o = __shfl_xor(accB[r], 32, 64);   // lo-residual rows
          sx[nt*4 + r] = sx[nt*4 + r]*rsu[r] + (accB[r] + o);
        }
      }
    }
  }

  // ---- final partial stores (one set per wave) ----
  const int pbase = (b*NBLK + wave_id)*8;
  if ((lid & 31) == 31) {
    #pragma unroll
    for (int hl = 0; hl < 4; ++hl) {
      const int h = hg*4 + hl;
      Pm[pbase + h] = Mh[hl];
      Pl[pbase + h] = Lh[hl];
      Psp[(pbase + h)*2 + 0] = gxf * Lh[hl];
      Psp[(pbase + h)*2 + 1] = SJh[hl];
    }
  }
  if (q4 < 2) {
    const size_t pb64 = (size_t)pbase * 64;
    #pragma unroll
    for (int nt = 0; nt < 4; ++nt)
      #pragma unroll
      for (int r = 0; r < 4; ++r)
        Psx[pb64 + (q4*4 + r)*64 + nt*16 + c0] = sx[nt*4 + r];
  }
}

// ---------------- K2a: combine 64 wave-partials per (b,h,g) ----------------
__global__ __launch_bounds__(256) void reduce1_kernel(
    const float* __restrict__ Pm, const float* __restrict__ Pl,
    const float* __restrict__ Psp, const float* __restrict__ Psx,
    float* __restrict__ Q)
{
  const int g = blockIdx.x, h = blockIdx.y, b = blockIdx.z, t = threadIdx.x;
  __shared__ float al[64];
  __shared__ float mgs;
  __shared__ float sums[3];
  __shared__ float sxl[256];
  const int base = (b*NBLK + g*64)*8 + h;

  float m_t = -1e30f;
  if (t < 64) {
    m_t = Pm[base + t*8];
    float mm = m_t;
    #pragma unroll
    for (int off = 32; off >= 1; off >>= 1) mm = fmaxf(mm, __shfl_xor(mm, off, 64));
    if (t == 0) mgs = mm;
  }
  __syncthreads();
  const float Mg = mgs;
  if (t < 64) {
    const float a = __expf(m_t - Mg);
    al[t] = a;
    float lt = Pl[base + t*8] * a;
    float sxv = Psp[(base + t*8)*2 + 0] * a;
    float syv = Psp[(base + t*8)*2 + 1] * a;
    #pragma unroll
    for (int off = 32; off >= 1; off >>= 1) {
      lt  += __shfl_xor(lt, off, 64);
      sxv += __shfl_xor(sxv, off, 64);
      syv += __shfl_xor(syv, off, 64);
    }
    if (t == 0) { sums[0] = lt; sums[1] = sxv; sums[2] = syv; }
  }
  __syncthreads();
  {
    const int c = t & 63, g2 = t >> 6;
    float acc = 0.f;
    #pragma unroll
    for (int i = 0; i < 16; ++i) {
      const int k = g2*16 + i;
      acc += al[k] * Psx[(size_t)(base + k*8)*64 + c];
    }
    sxl[g2*64 + c] = acc;
  }
  __syncthreads();
  float* q = Q + ((b*8 + h)*8 + g)*QSTR;
  if (t < 64) q[4+t] = sxl[t] + sxl[64+t] + sxl[128+t] + sxl[192+t];
  if (t == 0) { q[0] = Mg; q[1] = sums[0]; q[2] = sums[1]; q[3] = sums[2]; }
}

// ---------------- K2b: final combine + value projection ----------------
__global__ __launch_bounds__(64) void reduce2_kernel(
    const float* __restrict__ Q, const float* __restrict__ Wv, const float* __restrict__ bv,
    float* __restrict__ out)
{
  const int h = blockIdx.x, b = blockIdx.y, t = threadIdx.x;
  __shared__ float qm[8], bl[8], l8[8], sx8[8], sy8[8];
  __shared__ float SXs[64];
  const float* qb = Q + ((b*8 + h)*8)*QSTR;

  if (t < 8) qm[t] = qb[t*QSTR + 0];
  __syncthreads();
  float M = qm[0];
  #pragma unroll
  for (int g = 1; g < 8; ++g) M = fmaxf(M, qm[g]);
  if (t < 8) {
    const float be = __expf(qm[t] - M);
    bl[t]  = be;
    l8[t]  = be * qb[t*QSTR + 1];
    sx8[t] = be * qb[t*QSTR + 2];
    sy8[t] = be * qb[t*QSTR + 3];
  }
  __syncthreads();
  float L = 0.f;
  #pragma unroll
  for (int g = 0; g < 8; ++g) L += l8[g];
  const float invL = 1.0f / L;
  {
    float s = 0.f;
    #pragma unroll
    for (int g = 0; g < 8; ++g) s += bl[g] * qb[g*QSTR + 4 + t];
    SXs[t] = s * invL;
  }
  __syncthreads();

  #pragma unroll
  for (int r = 0; r < 4; ++r) {
    const int e = t + 64*r;
    float v = bv[e];
    const float* wvr = Wv + e*64;
    #pragma unroll 8
    for (int c = 0; c < 64; ++c) v += wvr[c] * SXs[c];
    out[(b*8 + h)*256 + e] = v;
  }
  if (t == 0) {
    float spx = 0.f, spy = 0.f;
    #pragma unroll
    for (int g = 0; g < 8; ++g) { spx += sx8[g]; spy += sy8[g]; }
    out[16384 + (b*8 + h)*2 + 0] = spx * invL;
    out[16384 + (b*8 + h)*2 + 1] = spy * invL;
  }
}

extern "C" void kernel_launch(void* const* d_in, const int* in_sizes, int n_in,
                              void* d_out, int out_size, void* d_ws, size_t ws_size,
                              hipStream_t stream)
{
  const float* x   = (const float*)d_in[0];
  const float* z   = (const float*)d_in[1];
  const float* pos = (const float*)d_in[2];
  const float* Wq  = (const float*)d_in[3];
  const float* bq  = (const float*)d_in[4];
  const float* Wk  = (const float*)d_in[5];
  const float* bk  = (const float*)d_in[6];
  const float* Wv  = (const float*)d_in[7];
  const float* bv  = (const float*)d_in[8];
  const float* Wp  = (const float*)d_in[9];
  const float* bp  = (const float*)d_in[10];
  float* out = (float*)d_out;
  char*  wsb = (char*)d_ws;

  ushort_t* WThi = (ushort_t*)(wsb + WTHI_B);
  ushort_t* WTlo = (ushort_t*)(wsb + WTLO_B);
  float* Cj  = (float*)(wsb + CJ_B);
  float* Pm  = (float*)(wsb + PM_B);
  float* Pl  = (float*)(wsb + PL_B);
  float* Psp = (float*)(wsb + PSP_B);
  float* Psx = (float*)(wsb + PSX_B);
  float* Q   = (float*)(wsb + Q_B);

  prep_kernel   <<<dim3(8,8),   64,  0,          stream>>>(z, Wq, bq, Wk, bk, Wp, bp, WThi, WTlo, Cj);
  main_kernel   <<<dim3(128,8), 256, SMEM_BYTES, stream>>>(x, pos, WThi, WTlo, Cj, Pm, Pl, Psp, Psx);
  reduce1_kernel<<<dim3(8,8,8), 256, 0,          stream>>>(Pm, Pl, Psp, Psx, Q);
  reduce2_kernel<<<dim3(8,8),   64,  0,          stream>>>(Q, Wv, bv, out);
}

// Round 8
// 238.201 us; speedup vs baseline: 1.1642x; 1.1642x over previous
//
#include <hip/hip_runtime.h>

// Problem constants
#define NN    65536       // H*W (H=W=256)
#define NSUB  256         // n per block
#define NBLK  (NN/NSUB)   // 256 blocks per batch

typedef short bf16x8 __attribute__((ext_vector_type(8)));
typedef float f32x4v __attribute__((ext_vector_type(4)));
typedef unsigned short ushort_t;
typedef unsigned int uint_t;

// ---- main_kernel LDS layout (bytes) ----
#define XSTR   72                 // xs row stride in bf16 units (144 B)
#define XHI_B  0                  // bf16 [256][72] = 36864 B
#define XLO_B  36864              // bf16 [256][72] = 36864 B (aliased by lga/p_lds)
#define LGA_B  36864              // f32  [256][28] = 28672 B
#define LGSTR  28
#define PSTR   264                // p_lds row stride (bf16): 528 B, 16B-aligned
#define RED_B  73728              // f32 red[96]
#define SMEM_BYTES 74112          // 2 blocks/CU = 8 waves/CU, 256-VGPR headroom

// ---- workspace byte offsets (generously sized; NBLK=256 uses less) ----
#define WTHI_B  0                 // bf16 [8][32][64] = 32768 B
#define WTLO_B  32768
#define CJ_B    65536             // f32 [8][24]
#define PM_B    66304
#define PL_B    197376
#define PSP_B   328448
#define PSX_B   590592
#define Q_B     8979200           // f32 [8][8][8][68]
#define QSTR    68

// ---------- helpers ----------
__device__ __forceinline__ uint_t bf16_rne_bits(float f) {
  uint_t u = __float_as_uint(f);
  return (u + 0x7FFFu + ((u >> 16) & 1u)) >> 16;
}
// packed f32->bf16 RNE (identical rounding to bf16_rne_bits), 1 inst per pair
__device__ __forceinline__ uint_t cvt_pk_bf16(float a, float b) {
  uint_t r;
  asm("v_cvt_pk_bf16_f32 %0, %1, %2" : "=v"(r) : "v"(a), "v"(b));
  return r;
}
template <int CTRL>
__device__ __forceinline__ float dpp_add(float x) {
  int t = __builtin_amdgcn_update_dpp(0, __float_as_int(x), CTRL, 0xf, 0xf, false);
  return x + __int_as_float(t);
}
template <int CTRL>
__device__ __forceinline__ float dpp_maxs(float x) {
  int t = __builtin_amdgcn_update_dpp((int)0xFF800000u, __float_as_int(x), CTRL, 0xf, 0xf, false);
  return fmaxf(x, __int_as_float(t));
}
__device__ __forceinline__ float wave_sum(float x) {
  x = dpp_add<0x111>(x); x = dpp_add<0x112>(x); x = dpp_add<0x114>(x);
  x = dpp_add<0x118>(x); x = dpp_add<0x142>(x); x = dpp_add<0x143>(x);
  return __int_as_float(__builtin_amdgcn_readlane(__float_as_int(x), 63));
}
__device__ __forceinline__ float wave_max(float x) {
  x = dpp_maxs<0x111>(x); x = dpp_maxs<0x112>(x); x = dpp_maxs<0x114>(x);
  x = dpp_maxs<0x118>(x); x = dpp_maxs<0x142>(x); x = dpp_maxs<0x143>(x);
  return __int_as_float(__builtin_amdgcn_readlane(__float_as_int(x), 63));
}

// ---------------- K0: effective weights, split-bf16, B-fragment layout ----------------
__global__ __launch_bounds__(64) void prep_kernel(
    const float* __restrict__ z,  const float* __restrict__ Wq, const float* __restrict__ bq,
    const float* __restrict__ Wk, const float* __restrict__ bk,
    const float* __restrict__ Wp, const float* __restrict__ bp,
    ushort_t* __restrict__ WThi, ushort_t* __restrict__ WTlo, float* __restrict__ Cj)
{
  const int h = blockIdx.x, b = blockIdx.y, t = threadIdx.x;
  __shared__ float q[32];
  if (t < 32) {
    const int e = h*32 + t;
    float a = bq[e];
    const float* zr = z + b*64;
    const float* wr = Wq + e*64;
    #pragma unroll 8
    for (int c = 0; c < 64; ++c) a += zr[c]*wr[c];
    q[t] = a;
  }
  __syncthreads();
  const int c = t;
  float w[3] = {0.f, 0.f, 0.f};
  #pragma unroll 4
  for (int hd = 0; hd < 32; ++hd) {
    const float qk = q[hd] * Wk[(h*32+hd)*64 + c];
    w[0] += qk * bp[hd];
    w[1] += qk * Wp[hd*2+0];
    w[2] += qk * Wp[hd*2+1];
  }
  #pragma unroll
  for (int j = 0; j < 3; ++j) {
    const int coeff = h*3 + j;
    const uint_t hb = bf16_rne_bits(w[j]);
    const float  fh = __uint_as_float(hb << 16);
    const uint_t lb = bf16_rne_bits(w[j] - fh);
    WThi[(b*32 + coeff)*64 + c] = (ushort_t)hb;
    WTlo[(b*32 + coeff)*64 + c] = (ushort_t)lb;
  }
  if (h == 0) {
    #pragma unroll
    for (int r = 0; r < 8; ++r) {
      WThi[(b*32 + 24 + r)*64 + c] = 0;
      WTlo[(b*32 + 24 + r)*64 + c] = 0;
    }
  }
  if (t < 3) {
    float s = 0.f;
    for (int hd = 0; hd < 32; ++hd) {
      const float m = (t == 0) ? bp[hd] : Wp[hd*2 + (t-1)];
      s += q[hd] * m * bk[h*32+hd];
    }
    Cj[b*24 + h*3 + t] = s;
  }
}

// ---------------- K1: 1KB-contiguous channel-sliced staging + MFMA phases ----------------
// 256 threads / 4 waves, 256 px per block, 2 blocks/CU.
// Staging: wave w loads channels [16w,16w+16): each load = 64 lanes x 16B = 1KB
// contiguous of one channel row (vs 512B half-wave segments in prior rounds).
__global__ __launch_bounds__(256, 2) void main_kernel(
    const float* __restrict__ x, const float* __restrict__ pos,
    const ushort_t* __restrict__ WThi, const ushort_t* __restrict__ WTlo,
    const float* __restrict__ Cj,
    float* __restrict__ Pm, float* __restrict__ Pl,
    float* __restrict__ Psp, float* __restrict__ Psx)
{
  extern __shared__ char smc[];
  ushort_t* xhi = (ushort_t*)(smc + XHI_B);
  float*    lga = (float*)(smc + LGA_B);
  float*    red = (float*)(smc + RED_B);
  const int t   = threadIdx.x;
  const int blk = blockIdx.x;
  const int b   = blockIdx.y;
  const int n0  = blk * NSUB;
  const int wid = t >> 6, lid = t & 63;
  const int c0  = lid & 15, q4 = lid >> 4;

  // ---- B-fragments (global, L2-hot) ----
  bf16x8 bh[2][2], bl[2][2];
  {
    const ushort_t* wtb_h = WThi + b*2048;
    const ushort_t* wtb_l = WTlo + b*2048;
    #pragma unroll
    for (int nt = 0; nt < 2; ++nt)
      #pragma unroll
      for (int ks = 0; ks < 2; ++ks) {
        const int off = (nt*16 + c0)*64 + ks*32 + q4*8;
        bh[nt][ks] = *(const bf16x8*)(wtb_h + off);
        bl[nt][ks] = *(const bf16x8*)(wtb_l + off);
      }
  }

  // ---- stage: wave wid -> channels [wid*16, wid*16+16), lane lid -> px 4*lid..+4 ----
  {
    const float* xg = x + (size_t)b*64*NN + (size_t)(wid*16)*NN + n0 + 4*lid;
    f32x4v v[16];
    #pragma unroll
    for (int c = 0; c < 16; ++c) v[c] = *(const f32x4v*)(xg + (size_t)c*NN);
    #pragma unroll
    for (int i = 0; i < 4; ++i) {
      uint_t H[8], L[8];
      #pragma unroll
      for (int jp = 0; jp < 8; ++jp) {
        const float f0 = v[2*jp][i], f1 = v[2*jp+1][i];
        const uint_t hpk = cvt_pk_bf16(f0, f1);
        const float h0 = __uint_as_float(hpk << 16);
        const float h1 = __uint_as_float(hpk & 0xFFFF0000u);
        const uint_t l0 = __float_as_uint(f0 - h0);
        const uint_t l1 = __float_as_uint(f1 - h1);
        H[jp] = hpk;
        L[jp] = __builtin_amdgcn_perm(l1, l0, 0x07060302u);  // {hi16(l1),hi16(l0)}
      }
      const int row = 4*lid + i;
      char* dh = smc + XHI_B + row*144 + wid*32;
      char* dl = smc + XLO_B + row*144 + wid*32;
      *(uint4*)(dh)      = make_uint4(H[0], H[1], H[2], H[3]);
      *(uint4*)(dh + 16) = make_uint4(H[4], H[5], H[6], H[7]);
      *(uint4*)(dl)      = make_uint4(L[0], L[1], L[2], L[3]);
      *(uint4*)(dl + 16) = make_uint4(L[4], L[5], L[6], L[7]);
    }
  }

  // ---- block-uniform params ----
  float cj[24];
  {
    const float* cjp = Cj + b*24;
    #pragma unroll
    for (int k = 0; k < 24; ++k) cj[k] = cjp[k];
  }
  float rxh[8], py[8];
  #pragma unroll
  for (int h = 0; h < 8; ++h) {
    rxh[h] = (float)blk - pos[(b*8+h)*2 + 0];   // gx == n>>8 == blk
    py[h]  = pos[(b*8+h)*2 + 1];
  }

  __syncthreads();   // (1) xs ready

  // ---- phase A: D[px, coeff] = X(hi+lo) . W^T(hi+lo); each wave 64 px rows ----
  f32x4v acc[4][2];
  #pragma unroll
  for (int mt = 0; mt < 4; ++mt) { acc[mt][0] = (f32x4v)0.f; acc[mt][1] = (f32x4v)0.f; }
  {
    const int mrow0 = wid*64;
    #pragma unroll
    for (int mt = 0; mt < 4; ++mt) {
      const int row = mrow0 + mt*16 + c0;
      const ushort_t* ph = xhi + row*XSTR + q4*8;
      const ushort_t* pl = (ushort_t*)(smc + XLO_B) + row*XSTR + q4*8;
      bf16x8 ah0 = *(const bf16x8*)(ph);
      bf16x8 ah1 = *(const bf16x8*)(ph + 32);
      bf16x8 al0 = *(const bf16x8*)(pl);
      bf16x8 al1 = *(const bf16x8*)(pl + 32);
      #pragma unroll
      for (int nt = 0; nt < 2; ++nt) {
        f32x4v a = acc[mt][nt];
        a = __builtin_amdgcn_mfma_f32_16x16x32_bf16(ah0, bh[nt][0], a, 0, 0, 0);
        a = __builtin_amdgcn_mfma_f32_16x16x32_bf16(ah1, bh[nt][1], a, 0, 0, 0);
        a = __builtin_amdgcn_mfma_f32_16x16x32_bf16(ah0, bl[nt][0], a, 0, 0, 0);
        a = __builtin_amdgcn_mfma_f32_16x16x32_bf16(ah1, bl[nt][1], a, 0, 0, 0);
        a = __builtin_amdgcn_mfma_f32_16x16x32_bf16(al0, bh[nt][0], a, 0, 0, 0);
        a = __builtin_amdgcn_mfma_f32_16x16x32_bf16(al1, bh[nt][1], a, 0, 0, 0);
        acc[mt][nt] = a;
      }
    }
  }
  __syncthreads();   // (2) all xlo reads done -> safe to alias lga

  // C-layout: col(coeff) = lane&15 (+16*nt), row(px) = quad*4 + reg
  {
    const int mrow0 = wid*64;
    #pragma unroll
    for (int mt = 0; mt < 4; ++mt)
      #pragma unroll
      for (int r = 0; r < 4; ++r) {
        const int prow = mrow0 + mt*16 + q4*4 + r;
        lga[prow*LGSTR + c0] = acc[mt][0][r];
        if (c0 < 8) lga[prow*LGSTR + 16 + c0] = acc[mt][1][r];
      }
  }
  __syncthreads();   // (3) lga ready

  // ---- per-thread logit assembly (pixel = n0 + t) ----
  float a24[24];
  {
    const float4* ap = (const float4*)(lga + t*LGSTR);
    #pragma unroll
    for (int r = 0; r < 6; ++r) *(float4*)(a24 + 4*r) = ap[r];
  }
  const float tf = (float)t;            // gy == n&255 == t
  float lg[8];
  #pragma unroll
  for (int h = 0; h < 8; ++h) {
    const float a0 = a24[h*3+0] + cj[h*3+0];
    const float a1 = a24[h*3+1] + cj[h*3+1];
    const float a2 = a24[h*3+2] + cj[h*3+2];
    lg[h] = (a0 + rxh[h]*a1 + (tf - py[h])*a2) * 0.17677669529663687f;
  }

  // ---- block max per head ----
  #pragma unroll
  for (int h = 0; h < 8; ++h) {
    const float m = wave_max(lg[h]);
    if (lid == 0) red[h*4 + wid] = m;
  }
  __syncthreads();   // (4) — all lga reads complete before this point

  float p[8];
  #pragma unroll
  for (int h = 0; h < 8; ++h) {
    const float M = fmaxf(fmaxf(red[h*4+0], red[h*4+1]), fmaxf(red[h*4+2], red[h*4+3]));
    p[h] = __expf(lg[h] - M);
  }

  // ---- P -> bf16 hi/lo into p_lds [16][PSTR] (rows 0-7 hi, 8-15 lo residual) ----
  {
    ushort_t* pls = (ushort_t*)(smc + LGA_B);
    #pragma unroll
    for (int h = 0; h < 8; ++h) {
      const uint_t hb = bf16_rne_bits(p[h]);
      const float  hf = __uint_as_float(hb << 16);
      const uint_t lb = __float_as_uint(p[h] - hf) >> 16;
      pls[h*PSTR + t]     = (ushort_t)hb;
      pls[(h+8)*PSTR + t] = (ushort_t)lb;
    }
  }

  #pragma unroll
  for (int h = 0; h < 8; ++h) {
    const float sp  = wave_sum(p[h]);
    const float spj = wave_sum(p[h] * tf);
    if (lid == 0) { red[32 + h*4 + wid] = sp; red[64 + h*4 + wid] = spj; }
  }
  __syncthreads();   // (5) red + p_lds ready

  if (t < 8) {
    const int base = (b*NBLK + blk)*8 + t;
    const float M  = fmaxf(fmaxf(red[t*4+0], red[t*4+1]), fmaxf(red[t*4+2], red[t*4+3]));
    const float L  = red[32+t*4+0] + red[32+t*4+1] + red[32+t*4+2] + red[32+t*4+3];
    const float SJ = red[64+t*4+0] + red[64+t*4+1] + red[64+t*4+2] + red[64+t*4+3];
    Pm[base] = M;
    Pl[base] = L;
    Psp[base*2+0] = (float)blk * L;
    Psp[base*2+1] = SJ;
  }

  // ---- phase B (MFMA): per wave D[16][16] = P(16x256) . Xhi(256 x 16-ch slice) ----
  // Full K=256 per wave -> result complete for its channel slice; Psx written directly.
  {
    const ushort_t* pls = (const ushort_t*)(smc + LGA_B);
    bf16x8 afr[8];
    #pragma unroll
    for (int ks = 0; ks < 8; ++ks)
      afr[ks] = *(const bf16x8*)(pls + c0*PSTR + ks*32 + q4*8);

    f32x4v accB = (f32x4v)0.f;
    const int ch = wid*16 + c0;          // wave owns channels [wid*16, wid*16+16)
    #pragma unroll
    for (int ks = 0; ks < 8; ++ks) {
      const ushort_t* xcol = xhi + (ks*32 + q4*8)*XSTR + ch;
      bf16x8 bfr;
      #pragma unroll
      for (int j = 0; j < 8; ++j) bfr[j] = (short)xcol[j*XSTR];
      accB = __builtin_amdgcn_mfma_f32_16x16x32_bf16(afr[ks], bfr, accB, 0, 0, 0);
    }

    // combine hi rows (lanes 0-31) with lo rows (lanes 32-63), store Psx[h][ch]
    const size_t pb64 = ((size_t)(b*NBLK + blk))*8*64;
    #pragma unroll
    for (int r = 0; r < 4; ++r) {
      const float o = __shfl_xor(accB[r], 32, 64);
      if (q4 < 2) {
        const int h = q4*4 + r;
        Psx[pb64 + h*64 + ch] = accB[r] + o;
      }
    }
  }
}

// ---------------- K2a: combine 32 blocks per (b,h,g) ----------------
__global__ __launch_bounds__(256) void reduce1_kernel(
    const float* __restrict__ Pm, const float* __restrict__ Pl,
    const float* __restrict__ Psp, const float* __restrict__ Psx,
    float* __restrict__ Q)
{
  const int g = blockIdx.x, h = blockIdx.y, b = blockIdx.z, t = threadIdx.x;
  __shared__ float al[32];
  __shared__ float mgs;
  __shared__ float sums[3];
  __shared__ float sxl[256];
  const int base = (b*NBLK + g*32)*8 + h;

  float m_t = -1e30f;
  if (t < 32) m_t = Pm[base + t*8];
  if (t < 64) {
    float mm = m_t;
    #pragma unroll
    for (int off = 16; off >= 1; off >>= 1) mm = fmaxf(mm, __shfl_xor(mm, off, 64));
    if (t == 0) mgs = mm;
  }
  __syncthreads();
  const float Mg = mgs;
  if (t < 32) {
    const float a = __expf(m_t - Mg);
    al[t] = a;
    float lt = Pl[base + t*8] * a;
    float sx = Psp[(base + t*8)*2 + 0] * a;
    float sy = Psp[(base + t*8)*2 + 1] * a;
    #pragma unroll
    for (int off = 16; off >= 1; off >>= 1) {
      lt += __shfl_xor(lt, off, 64);
      sx += __shfl_xor(sx, off, 64);
      sy += __shfl_xor(sy, off, 64);
    }
    if (t == 0) { sums[0] = lt; sums[1] = sx; sums[2] = sy; }
  }
  __syncthreads();
  {
    const int c = t & 63, g2 = t >> 6;
    float acc = 0.f;
    #pragma unroll
    for (int i = 0; i < 8; ++i) {
      const int k = g2*8 + i;
      acc += al[k] * Psx[(size_t)(base + k*8)*64 + c];
    }
    sxl[g2*64 + c] = acc;
  }
  __syncthreads();
  float* q = Q + ((b*8 + h)*8 + g)*QSTR;
  if (t < 64) q[4+t] = sxl[t] + sxl[64+t] + sxl[128+t] + sxl[192+t];
  if (t == 0) { q[0] = Mg; q[1] = sums[0]; q[2] = sums[1]; q[3] = sums[2]; }
}

// ---------------- K2b: final combine + value projection ----------------
__global__ __launch_bounds__(64) void reduce2_kernel(
    const float* __restrict__ Q, const float* __restrict__ Wv, const float* __restrict__ bv,
    float* __restrict__ out)
{
  const int h = blockIdx.x, b = blockIdx.y, t = threadIdx.x;
  __shared__ float qm[8], bl[8], l8[8], sx8[8], sy8[8];
  __shared__ float SXs[64];
  const float* qb = Q + ((b*8 + h)*8)*QSTR;

  if (t < 8) qm[t] = qb[t*QSTR + 0];
  __syncthreads();
  float M = qm[0];
  #pragma unroll
  for (int g = 1; g < 8; ++g) M = fmaxf(M, qm[g]);
  if (t < 8) {
    const float be = __expf(qm[t] - M);
    bl[t]  = be;
    l8[t]  = be * qb[t*QSTR + 1];
    sx8[t] = be * qb[t*QSTR + 2];
    sy8[t] = be * qb[t*QSTR + 3];
  }
  __syncthreads();
  float L = 0.f;
  #pragma unroll
  for (int g = 0; g < 8; ++g) L += l8[g];
  const float invL = 1.0f / L;
  {
    float s = 0.f;
    #pragma unroll
    for (int g = 0; g < 8; ++g) s += bl[g] * qb[g*QSTR + 4 + t];
    SXs[t] = s * invL;
  }
  __syncthreads();

  #pragma unroll
  for (int r = 0; r < 4; ++r) {
    const int e = t + 64*r;
    float v = bv[e];
    const float* wvr = Wv + e*64;
    #pragma unroll 8
    for (int c = 0; c < 64; ++c) v += wvr[c] * SXs[c];
    out[(b*8 + h)*256 + e] = v;
  }
  if (t == 0) {
    float spx = 0.f, spy = 0.f;
    #pragma unroll
    for (int g = 0; g < 8; ++g) { spx += sx8[g]; spy += sy8[g]; }
    out[16384 + (b*8 + h)*2 + 0] = spx * invL;
    out[16384 + (b*8 + h)*2 + 1] = spy * invL;
  }
}

extern "C" void kernel_launch(void* const* d_in, const int* in_sizes, int n_in,
                              void* d_out, int out_size, void* d_ws, size_t ws_size,
                              hipStream_t stream)
{
  const float* x   = (const float*)d_in[0];
  const float* z   = (const float*)d_in[1];
  const float* pos = (const float*)d_in[2];
  const float* Wq  = (const float*)d_in[3];
  const float* bq  = (const float*)d_in[4];
  const float* Wk  = (const float*)d_in[5];
  const float* bk  = (const float*)d_in[6];
  const float* Wv  = (const float*)d_in[7];
  const float* bv  = (const float*)d_in[8];
  const float* Wp  = (const float*)d_in[9];
  const float* bp  = (const float*)d_in[10];
  float* out = (float*)d_out;
  char*  wsb = (char*)d_ws;

  ushort_t* WThi = (ushort_t*)(wsb + WTHI_B);
  ushort_t* WTlo = (ushort_t*)(wsb + WTLO_B);
  float* Cj  = (float*)(wsb + CJ_B);
  float* Pm  = (float*)(wsb + PM_B);
  float* Pl  = (float*)(wsb + PL_B);
  float* Psp = (float*)(wsb + PSP_B);
  float* Psx = (float*)(wsb + PSX_B);
  float* Q   = (float*)(wsb + Q_B);

  // 74112 B dynamic LDS (> 64 KB default) — host-side, graph-safe, idempotent
  (void)hipFuncSetAttribute((const void*)main_kernel,
                            hipFuncAttributeMaxDynamicSharedMemorySize, SMEM_BYTES);

  prep_kernel   <<<dim3(8,8),    64,  0,          stream>>>(z, Wq, bq, Wk, bk, Wp, bp, WThi, WTlo, Cj);
  main_kernel   <<<dim3(NBLK,8), 256, SMEM_BYTES, stream>>>(x, pos, WThi, WTlo, Cj, Pm, Pl, Psp, Psx);
  reduce1_kernel<<<dim3(8,8,8),  256, 0,          stream>>>(Pm, Pl, Psp, Psx, Q);
  reduce2_kernel<<<dim3(8,8),    64,  0,          stream>>>(Q, Wv, bv, out);
}

// Round 9
// 233.080 us; speedup vs baseline: 1.1898x; 1.0220x over previous
//
#include <hip/hip_runtime.h>

// Problem constants
#define NN    65536       // H*W (H=W=256)
#define NSUB  128         // n per block (3 blocks/CU)
#define NBLK  (NN/NSUB)   // 512 blocks per batch

typedef short bf16x8 __attribute__((ext_vector_type(8)));
typedef float f32x4v __attribute__((ext_vector_type(4)));
typedef unsigned short ushort_t;
typedef unsigned int uint_t;

// ---- main_kernel LDS layout (bytes) ----
#define XSTR   72                 // xs row stride in bf16 units (144 B)
#define XHI_B  0                  // bf16 [128][72]  = 18432 B
#define XLO_B  18432              // bf16 [128][72]  = 18432 B (aliased by lga, then p_lds)
#define LGA_B  18432              // f32  [128][28]  = 14336 B (dead after logit read)
#define LGSTR  28
#define PSTR   136                // p_lds row stride in bf16 units (272 B, 16B-aligned)
#define F32C_B 36864              // f32 staging chunks: 2 x [16 ch][128 px] = 16384 B
#define RED_B  53248              // f32 red[48]
#define SMEM_BYTES 53632          // 3 blocks/CU = 12 waves/CU

// ---- workspace byte offsets ----
#define WTHI_B  0                 // bf16 [8][32][64] = 32768 B
#define WTLO_B  32768
#define CJ_B    65536             // f32 [8][24]
#define PM_B    66304             // f32 [8*NBLK*8] = 131072 B
#define PL_B    197376
#define PSP_B   328448            // f32 [..][2] = 262144 B
#define PSX_B   590592            // f32 [..][64] = 8 MB
#define Q_B     8979200           // f32 [8][8][8][68]
#define QSTR    68

// ---------- helpers ----------
__device__ __forceinline__ uint_t bf16_rne_bits(float f) {
  uint_t u = __float_as_uint(f);
  return (u + 0x7FFFu + ((u >> 16) & 1u)) >> 16;
}
// packed f32->bf16 RNE (identical rounding to bf16_rne_bits), 1 inst per pair
__device__ __forceinline__ uint_t cvt_pk_bf16(float a, float b) {
  uint_t r;
  asm("v_cvt_pk_bf16_f32 %0, %1, %2" : "=v"(r) : "v"(a), "v"(b));
  return r;
}
template <int CTRL>
__device__ __forceinline__ float dpp_add(float x) {
  int t = __builtin_amdgcn_update_dpp(0, __float_as_int(x), CTRL, 0xf, 0xf, false);
  return x + __int_as_float(t);
}
template <int CTRL>
__device__ __forceinline__ float dpp_maxs(float x) {
  int t = __builtin_amdgcn_update_dpp((int)0xFF800000u, __float_as_int(x), CTRL, 0xf, 0xf, false);
  return fmaxf(x, __int_as_float(t));
}
__device__ __forceinline__ float wave_sum(float x) {
  x = dpp_add<0x111>(x); x = dpp_add<0x112>(x); x = dpp_add<0x114>(x);
  x = dpp_add<0x118>(x); x = dpp_add<0x142>(x); x = dpp_add<0x143>(x);
  return __int_as_float(__builtin_amdgcn_readlane(__float_as_int(x), 63));
}
__device__ __forceinline__ float wave_max(float x) {
  x = dpp_maxs<0x111>(x); x = dpp_maxs<0x112>(x); x = dpp_maxs<0x114>(x);
  x = dpp_maxs<0x118>(x); x = dpp_maxs<0x142>(x); x = dpp_maxs<0x143>(x);
  return __int_as_float(__builtin_amdgcn_readlane(__float_as_int(x), 63));
}

// ---------------- K0: effective weights, split-bf16, B-fragment layout ----------------
__global__ __launch_bounds__(64) void prep_kernel(
    const float* __restrict__ z,  const float* __restrict__ Wq, const float* __restrict__ bq,
    const float* __restrict__ Wk, const float* __restrict__ bk,
    const float* __restrict__ Wp, const float* __restrict__ bp,
    ushort_t* __restrict__ WThi, ushort_t* __restrict__ WTlo, float* __restrict__ Cj)
{
  const int h = blockIdx.x, b = blockIdx.y, t = threadIdx.x;
  __shared__ float q[32];
  if (t < 32) {
    const int e = h*32 + t;
    float a = bq[e];
    const float* zr = z + b*64;
    const float* wr = Wq + e*64;
    #pragma unroll 8
    for (int c = 0; c < 64; ++c) a += zr[c]*wr[c];
    q[t] = a;
  }
  __syncthreads();
  const int c = t;
  float w[3] = {0.f, 0.f, 0.f};
  #pragma unroll 4
  for (int hd = 0; hd < 32; ++hd) {
    const float qk = q[hd] * Wk[(h*32+hd)*64 + c];
    w[0] += qk * bp[hd];
    w[1] += qk * Wp[hd*2+0];
    w[2] += qk * Wp[hd*2+1];
  }
  #pragma unroll
  for (int j = 0; j < 3; ++j) {
    const int coeff = h*3 + j;
    const uint_t hb = bf16_rne_bits(w[j]);
    const float  fh = __uint_as_float(hb << 16);
    const uint_t lb = bf16_rne_bits(w[j] - fh);
    WThi[(b*32 + coeff)*64 + c] = (ushort_t)hb;
    WTlo[(b*32 + coeff)*64 + c] = (ushort_t)lb;
  }
  if (h == 0) {
    #pragma unroll
    for (int r = 0; r < 8; ++r) {
      WThi[(b*32 + 24 + r)*64 + c] = 0;
      WTlo[(b*32 + 24 + r)*64 + c] = 0;
    }
  }
  if (t < 3) {
    float s = 0.f;
    for (int hd = 0; hd < 32; ++hd) {
      const float m = (t == 0) ? bp[hd] : Wp[hd*2 + (t-1)];
      s += q[hd] * m * bk[h*32+hd];
    }
    Cj[b*24 + h*3 + t] = s;
  }
}

// ---- async staging helpers (global_load_lds; counted vmcnt + raw barriers) ----
#define ISSUE_CHUNK(CI)                                                              \
  do {                                                                               \
    _Pragma("unroll")                                                                \
    for (int k = 0; k < 2; ++k) {                                                    \
      const int p  = wid*2 + k;                                                      \
      const int ch = (CI)*16 + 2*p + (lid >> 5);                                     \
      const float* gsrc = xbb + (size_t)ch*NN + (lid & 31)*4;                        \
      char* ldst = smc + F32C_B + ((CI)&1)*8192 + p*1024;                            \
      __builtin_amdgcn_global_load_lds(                                              \
          (const __attribute__((address_space(1))) void*)gsrc,                       \
          (__attribute__((address_space(3))) void*)ldst, 16, 0, 0);                  \
    }                                                                                \
  } while (0)

#define CONVERT_CHUNK(CI)                                                            \
  do {                                                                               \
    const float* f32c = (const float*)(smc + F32C_B + ((CI)&1)*8192);                \
    float vv[8];                                                                     \
    _Pragma("unroll")                                                                \
    for (int j = 0; j < 8; ++j) vv[j] = f32c[(hgrp*8 + j)*128 + px];                 \
    uint_t H[4], L[4];                                                               \
    _Pragma("unroll")                                                                \
    for (int jp = 0; jp < 4; ++jp) {                                                 \
      const float f0 = vv[2*jp], f1 = vv[2*jp+1];                                    \
      const uint_t hpk = cvt_pk_bf16(f0, f1);                                        \
      const float h0 = __uint_as_float(hpk << 16);                                   \
      const float h1 = __uint_as_float(hpk & 0xFFFF0000u);                           \
      const uint_t l0 = __float_as_uint(f0 - h0);                                    \
      const uint_t l1 = __float_as_uint(f1 - h1);                                    \
      H[jp] = hpk;                                                                   \
      L[jp] = __builtin_amdgcn_perm(l1, l0, 0x07060302u);                            \
    }                                                                                \
    char* dh = smc + XHI_B + px*144 + ((CI)*2 + hgrp)*16;                            \
    char* dl = smc + XLO_B + px*144 + ((CI)*2 + hgrp)*16;                            \
    *(uint4*)dh = make_uint4(H[0], H[1], H[2], H[3]);                                \
    *(uint4*)dl = make_uint4(L[0], L[1], L[2], L[3]);                                \
  } while (0)

// ---------------- K1: async-DMA staging + MFMA logits + softmax + MFMA weighted-x ----------------
__global__ __launch_bounds__(256, 3) void main_kernel(
    const float* __restrict__ x, const float* __restrict__ pos,
    const ushort_t* __restrict__ WThi, const ushort_t* __restrict__ WTlo,
    const float* __restrict__ Cj,
    float* __restrict__ Pm, float* __restrict__ Pl,
    float* __restrict__ Psp, float* __restrict__ Psx)
{
  extern __shared__ char smc[];
  float*    lga = (float*)(smc + LGA_B);
  float*    red = (float*)(smc + RED_B);
  const int t   = threadIdx.x;
  const int blk = blockIdx.x;
  const int b   = blockIdx.y;
  const int n0  = blk * NSUB;
  const int wid = t >> 6, lid = t & 63;
  const int c0  = lid & 15, q4 = lid >> 4;
  const int px  = t & 127;          // pixel owned for conversion / logits
  const int hgrp = t >> 7;          // 0: heads 0-3, 1: heads 4-7
  const int half = wid & 1;         // pixel half (0: px 0-63, 1: px 64-127)

  // ---- B-fragments + params first (older vmcnt entries; drained by first wait) ----
  bf16x8 bh[2][2], bl[2][2];
  {
    const ushort_t* wtb_h = WThi + b*2048;
    const ushort_t* wtb_l = WTlo + b*2048;
    #pragma unroll
    for (int nt = 0; nt < 2; ++nt)
      #pragma unroll
      for (int ks = 0; ks < 2; ++ks) {
        const int off = (nt*16 + c0)*64 + ks*32 + q4*8;
        bh[nt][ks] = *(const bf16x8*)(wtb_h + off);
        bl[nt][ks] = *(const bf16x8*)(wtb_l + off);
      }
  }
  float cj[12];
  {
    const float* cjp = Cj + b*24 + hgrp*12;
    #pragma unroll
    for (int k = 0; k < 12; ++k) cj[k] = cjp[k];
  }
  const int gx = blk >> 1;                      // n>>8 block-uniform
  float rxh[4], py[4];
  #pragma unroll
  for (int hl = 0; hl < 4; ++hl) {
    const int h = hgrp*4 + hl;
    rxh[hl] = (float)gx - pos[(b*8+h)*2 + 0];
    py[hl]  = pos[(b*8+h)*2 + 1];
  }

  // ---- async staging pipeline: 4 chunks of 16 ch, double-buffered f32 in LDS ----
  const float* xbb = x + (size_t)b*64*NN + n0;
  ISSUE_CHUNK(0);
  ISSUE_CHUNK(1);

  asm volatile("s_waitcnt vmcnt(2)" ::: "memory");   // chunk0 landed (chunk1 in flight)
  __builtin_amdgcn_sched_barrier(0);
  __builtin_amdgcn_s_barrier();
  CONVERT_CHUNK(0);
  asm volatile("s_waitcnt lgkmcnt(0)" ::: "memory"); // buf0 reads retired
  __builtin_amdgcn_s_barrier();
  ISSUE_CHUNK(2);                                    // reuse buf0

  asm volatile("s_waitcnt vmcnt(2)" ::: "memory");   // chunk1 landed (chunk2 in flight)
  __builtin_amdgcn_sched_barrier(0);
  __builtin_amdgcn_s_barrier();
  CONVERT_CHUNK(1);
  asm volatile("s_waitcnt lgkmcnt(0)" ::: "memory"); // buf1 reads retired
  __builtin_amdgcn_s_barrier();
  ISSUE_CHUNK(3);                                    // reuse buf1

  asm volatile("s_waitcnt vmcnt(2)" ::: "memory");   // chunk2 landed (chunk3 in flight)
  __builtin_amdgcn_sched_barrier(0);
  __builtin_amdgcn_s_barrier();
  CONVERT_CHUNK(2);

  asm volatile("s_waitcnt vmcnt(0)" ::: "memory");   // chunk3 landed
  __builtin_amdgcn_sched_barrier(0);
  __builtin_amdgcn_s_barrier();
  CONVERT_CHUNK(3);

  asm volatile("s_waitcnt lgkmcnt(0)" ::: "memory"); // all bf16 writes done
  __builtin_amdgcn_s_barrier();                      // (1) xs ready for all waves

  // ---- phase A: D[pixel, coeff] = X(hi+lo) . W^T(hi+lo); each wave: 32 pixel rows ----
  f32x4v acc[2][2];
  #pragma unroll
  for (int mt = 0; mt < 2; ++mt) { acc[mt][0] = (f32x4v)0.f; acc[mt][1] = (f32x4v)0.f; }
  {
    const int mrow0 = wid*32;
    #pragma unroll
    for (int mt = 0; mt < 2; ++mt) {
      const int row = mrow0 + mt*16 + c0;
      const ushort_t* ph = (const ushort_t*)(smc + XHI_B) + row*XSTR + q4*8;
      const ushort_t* pl = (const ushort_t*)(smc + XLO_B) + row*XSTR + q4*8;
      bf16x8 ah0 = *(const bf16x8*)(ph);
      bf16x8 ah1 = *(const bf16x8*)(ph + 32);
      bf16x8 al0 = *(const bf16x8*)(pl);
      bf16x8 al1 = *(const bf16x8*)(pl + 32);
      #pragma unroll
      for (int nt = 0; nt < 2; ++nt) {
        f32x4v a = acc[mt][nt];
        a = __builtin_amdgcn_mfma_f32_16x16x32_bf16(ah0, bh[nt][0], a, 0, 0, 0);
        a = __builtin_amdgcn_mfma_f32_16x16x32_bf16(ah1, bh[nt][1], a, 0, 0, 0);
        a = __builtin_amdgcn_mfma_f32_16x16x32_bf16(ah0, bl[nt][0], a, 0, 0, 0);
        a = __builtin_amdgcn_mfma_f32_16x16x32_bf16(ah1, bl[nt][1], a, 0, 0, 0);
        a = __builtin_amdgcn_mfma_f32_16x16x32_bf16(al0, bh[nt][0], a, 0, 0, 0);
        a = __builtin_amdgcn_mfma_f32_16x16x32_bf16(al1, bh[nt][1], a, 0, 0, 0);
        acc[mt][nt] = a;
      }
    }
  }
  __syncthreads();   // (2) xs_lo reads done -> safe to alias lga

  // C-layout: col(coeff) = lane&15 (+16*nt), row(pixel) = quad*4 + reg
  {
    const int mrow0 = wid*32;
    #pragma unroll
    for (int mt = 0; mt < 2; ++mt)
      #pragma unroll
      for (int r = 0; r < 4; ++r) {
        const int prow = mrow0 + mt*16 + q4*4 + r;
        lga[prow*LGSTR + c0] = acc[mt][0][r];
        if (c0 < 8) lga[prow*LGSTR + 16 + c0] = acc[mt][1][r];
      }
  }
  __syncthreads();   // (3) lga ready

  // ---- per-thread logit assembly (pixel = n0 + px, heads hgrp*4..+4) ----
  float a12[12];
  {
    const float4* ap = (const float4*)(lga + px*LGSTR + hgrp*12);
    #pragma unroll
    for (int r = 0; r < 3; ++r) *(float4*)(a12 + 4*r) = ap[r];
  }
  const float tf = (float)(((blk & 1) << 7) + px);   // gy = n & 255
  float lg[4];
  #pragma unroll
  for (int hl = 0; hl < 4; ++hl) {
    const float a0 = a12[hl*3+0] + cj[hl*3+0];
    const float a1 = a12[hl*3+1] + cj[hl*3+1];
    const float a2 = a12[hl*3+2] + cj[hl*3+2];
    lg[hl] = (a0 + rxh[hl]*a1 + (tf - py[hl])*a2) * 0.17677669529663687f;
  }

  // ---- block max per head (wave covers one pixel-half for its 4 heads) ----
  #pragma unroll
  for (int hl = 0; hl < 4; ++hl) {
    const float m = wave_max(lg[hl]);
    if (lid == 0) red[(hgrp*4 + hl)*2 + half] = m;
  }
  __syncthreads();   // (4) — all lga reads complete before this point

  float p[4];
  #pragma unroll
  for (int hl = 0; hl < 4; ++hl) {
    const int h = hgrp*4 + hl;
    const float M = fmaxf(red[h*2+0], red[h*2+1]);
    p[hl] = __expf(lg[hl] - M);
  }

  // ---- P -> bf16 hi/lo into p_lds [16][PSTR] (rows 0-7 hi, 8-15 lo residual) ----
  {
    ushort_t* pls = (ushort_t*)(smc + LGA_B);
    #pragma unroll
    for (int hl = 0; hl < 4; ++hl) {
      const int h = hgrp*4 + hl;
      const uint_t hb = bf16_rne_bits(p[hl]);
      const float  hf = __uint_as_float(hb << 16);
      const uint_t lb = __float_as_uint(p[hl] - hf) >> 16;
      pls[h*PSTR + px]       = (ushort_t)hb;
      pls[(h+8)*PSTR + px]   = (ushort_t)lb;
    }
  }

  #pragma unroll
  for (int hl = 0; hl < 4; ++hl) {
    const int h = hgrp*4 + hl;
    const float sp  = wave_sum(p[hl]);
    const float spj = wave_sum(p[hl] * tf);
    if (lid == 0) { red[16 + h*2 + half] = sp; red[32 + h*2 + half] = spj; }
  }
  __syncthreads();   // (5) red + p_lds ready

  if (t < 8) {
    const int base = (b*NBLK + blk)*8 + t;
    const float M  = fmaxf(red[t*2+0], red[t*2+1]);
    const float L  = red[16+t*2+0] + red[16+t*2+1];
    const float SJ = red[32+t*2+0] + red[32+t*2+1];
    Pm[base] = M;
    Pl[base] = L;
    Psp[base*2+0] = (float)gx * L;
    Psp[base*2+1] = SJ;
  }

  // ---- phase B (MFMA): D[16][16] per wave = P(16x128) . Xhi(128x16-chan slice) ----
  {
    const ushort_t* pls = (const ushort_t*)(smc + LGA_B);
    bf16x8 afr[4];
    #pragma unroll
    for (int ks = 0; ks < 4; ++ks)
      afr[ks] = *(const bf16x8*)(pls + c0*PSTR + ks*32 + q4*8);

    f32x4v accB = (f32x4v)0.f;
    const int chbase = wid*16 + c0;          // wave owns channels [wid*16, wid*16+16)
    #pragma unroll
    for (int ks = 0; ks < 4; ++ks) {
      const ushort_t* xcol = (const ushort_t*)(smc + XHI_B) + (ks*32 + q4*8)*XSTR + chbase;
      bf16x8 bfr;
      #pragma unroll
      for (int i = 0; i < 8; ++i) bfr[i] = (short)xcol[i*XSTR];
      accB = __builtin_amdgcn_mfma_f32_16x16x32_bf16(afr[ks], bfr, accB, 0, 0, 0);
    }

    // combine hi rows (lanes 0-31) with lo rows (lanes 32-63), store Psx[h][c]
    const size_t pb64 = ((size_t)(b*NBLK + blk))*8*64;
    #pragma unroll
    for (int r = 0; r < 4; ++r) {
      const float o = __shfl_xor(accB[r], 32, 64);
      if (q4 < 2) {
        const int h = q4*4 + r;
        Psx[pb64 + h*64 + chbase] = accB[r] + o;
      }
    }
  }
}

// ---------------- K2a: combine 64 blocks per (b,h,g) ----------------
__global__ __launch_bounds__(256) void reduce1_kernel(
    const float* __restrict__ Pm, const float* __restrict__ Pl,
    const float* __restrict__ Psp, const float* __restrict__ Psx,
    float* __restrict__ Q)
{
  const int g = blockIdx.x, h = blockIdx.y, b = blockIdx.z, t = threadIdx.x;
  __shared__ float al[64];
  __shared__ float mgs;
  __shared__ float sums[3];
  __shared__ float sxl[256];
  const int base = (b*NBLK + g*64)*8 + h;

  float m_t = -1e30f;
  if (t < 64) {
    m_t = Pm[base + t*8];
    float mm = m_t;
    #pragma unroll
    for (int off = 32; off >= 1; off >>= 1) mm = fmaxf(mm, __shfl_xor(mm, off, 64));
    if (t == 0) mgs = mm;
  }
  __syncthreads();
  const float Mg = mgs;
  if (t < 64) {
    const float a = __expf(m_t - Mg);
    al[t] = a;
    float lt = Pl[base + t*8] * a;
    float sx = Psp[(base + t*8)*2 + 0] * a;
    float sy = Psp[(base + t*8)*2 + 1] * a;
    #pragma unroll
    for (int off = 32; off >= 1; off >>= 1) {
      lt += __shfl_xor(lt, off, 64);
      sx += __shfl_xor(sx, off, 64);
      sy += __shfl_xor(sy, off, 64);
    }
    if (t == 0) { sums[0] = lt; sums[1] = sx; sums[2] = sy; }
  }
  __syncthreads();
  {
    const int c = t & 63, g2 = t >> 6;
    float acc = 0.f;
    #pragma unroll
    for (int i = 0; i < 16; ++i) {
      const int k = g2*16 + i;
      acc += al[k] * Psx[(size_t)(base + k*8)*64 + c];
    }
    sxl[g2*64 + c] = acc;
  }
  __syncthreads();
  float* q = Q + ((b*8 + h)*8 + g)*QSTR;
  if (t < 64) q[4+t] = sxl[t] + sxl[64+t] + sxl[128+t] + sxl[192+t];
  if (t == 0) { q[0] = Mg; q[1] = sums[0]; q[2] = sums[1]; q[3] = sums[2]; }
}

// ---------------- K2b: final combine + value projection ----------------
__global__ __launch_bounds__(64) void reduce2_kernel(
    const float* __restrict__ Q, const float* __restrict__ Wv, const float* __restrict__ bv,
    float* __restrict__ out)
{
  const int h = blockIdx.x, b = blockIdx.y, t = threadIdx.x;
  __shared__ float qm[8], bl[8], l8[8], sx8[8], sy8[8];
  __shared__ float SXs[64];
  const float* qb = Q + ((b*8 + h)*8)*QSTR;

  if (t < 8) qm[t] = qb[t*QSTR + 0];
  __syncthreads();
  float M = qm[0];
  #pragma unroll
  for (int g = 1; g < 8; ++g) M = fmaxf(M, qm[g]);
  if (t < 8) {
    const float be = __expf(qm[t] - M);
    bl[t]  = be;
    l8[t]  = be * qb[t*QSTR + 1];
    sx8[t] = be * qb[t*QSTR + 2];
    sy8[t] = be * qb[t*QSTR + 3];
  }
  __syncthreads();
  float L = 0.f;
  #pragma unroll
  for (int g = 0; g < 8; ++g) L += l8[g];
  const float invL = 1.0f / L;
  {
    float s = 0.f;
    #pragma unroll
    for (int g = 0; g < 8; ++g) s += bl[g] * qb[g*QSTR + 4 + t];
    SXs[t] = s * invL;
  }
  __syncthreads();

  #pragma unroll
  for (int r = 0; r < 4; ++r) {
    const int e = t + 64*r;
    float v = bv[e];
    const float* wvr = Wv + e*64;
    #pragma unroll 8
    for (int c = 0; c < 64; ++c) v += wvr[c] * SXs[c];
    out[(b*8 + h)*256 + e] = v;
  }
  if (t == 0) {
    float spx = 0.f, spy = 0.f;
    #pragma unroll
    for (int g = 0; g < 8; ++g) { spx += sx8[g]; spy += sy8[g]; }
    out[16384 + (b*8 + h)*2 + 0] = spx * invL;
    out[16384 + (b*8 + h)*2 + 1] = spy * invL;
  }
}

extern "C" void kernel_launch(void* const* d_in, const int* in_sizes, int n_in,
                              void* d_out, int out_size, void* d_ws, size_t ws_size,
                              hipStream_t stream)
{
  const float* x   = (const float*)d_in[0];
  const float* z   = (const float*)d_in[1];
  const float* pos = (const float*)d_in[2];
  const float* Wq  = (const float*)d_in[3];
  const float* bq  = (const float*)d_in[4];
  const float* Wk  = (const float*)d_in[5];
  const float* bk  = (const float*)d_in[6];
  const float* Wv  = (const float*)d_in[7];
  const float* bv  = (const float*)d_in[8];
  const float* Wp  = (const float*)d_in[9];
  const float* bp  = (const float*)d_in[10];
  float* out = (float*)d_out;
  char*  wsb = (char*)d_ws;

  ushort_t* WThi = (ushort_t*)(wsb + WTHI_B);
  ushort_t* WTlo = (ushort_t*)(wsb + WTLO_B);
  float* Cj  = (float*)(wsb + CJ_B);
  float* Pm  = (float*)(wsb + PM_B);
  float* Pl  = (float*)(wsb + PL_B);
  float* Psp = (float*)(wsb + PSP_B);
  float* Psx = (float*)(wsb + PSX_B);
  float* Q   = (float*)(wsb + Q_B);

  prep_kernel   <<<dim3(8,8),    64,  0,          stream>>>(z, Wq, bq, Wk, bk, Wp, bp, WThi, WTlo, Cj);
  main_kernel   <<<dim3(NBLK,8), 256, SMEM_BYTES, stream>>>(x, pos, WThi, WTlo, Cj, Pm, Pl, Psp, Psx);
  reduce1_kernel<<<dim3(8,8,8),  256, 0,          stream>>>(Pm, Pl, Psp, Psx, Q);
  reduce2_kernel<<<dim3(8,8),    64,  0,          stream>>>(Q, Wv, bv, out);
}